// Round 12
// baseline (214.007 us; speedup 1.0000x reference)
//
#include <hip/hip_runtime.h>
#include <math.h>

typedef __attribute__((ext_vector_type(8))) short bf16x8;
typedef __attribute__((ext_vector_type(4))) float f32x4;

__device__ __forceinline__ unsigned short f2b(float f) {
    unsigned int u = __float_as_uint(f);
    unsigned int r = (u + 0x7fffu + ((u >> 16) & 1u)) >> 16;   // RTNE
    return (unsigned short)r;
}
__device__ __forceinline__ float blo(unsigned int w) { return __uint_as_float(w << 16); }
__device__ __forceinline__ float bhi(unsigned int w) { return __uint_as_float(w & 0xffff0000u); }
__device__ __forceinline__ float b2f(unsigned short u) { return __uint_as_float((unsigned int)u << 16); }

__device__ __forceinline__ void gload_lds16(const void* g, void* lds) {
    __builtin_amdgcn_global_load_lds(
        (const __attribute__((address_space(1))) unsigned int*)g,
        (__attribute__((address_space(3))) unsigned int*)lds, 16, 0, 0);
}

// ---------------------------------------------------------------------------
// bf16 MFMA GEMM: out[M x NC] = epi(A[Mpad x K] @ W[K x NC] + bias)
// BT = W^T row-major [NC x K] bf16. Tile 128x128, BK=64, 4 waves, T2 swizzle.
// Single-buffered LDS (32 KB) -- 64KB double-buffer costs occupancy (r6).
// EPI: 1 = relu -> bf16 ws (unguarded, Mpad rows)
//      2 = bias -> bf16 ws (unguarded, Mpad rows)
//      3 = +res(bf16) + LayerNorm -> bf16 ws (pad rows zeroed)  [NC==128]
//      4 = +res(bf16) + LayerNorm -> f32 out (guard row<M)      [NC==128]
// ---------------------------------------------------------------------------
template<int K, int EPI>
__global__ __launch_bounds__(256)
void mfma_gemm(const unsigned short* __restrict__ A,
               const unsigned short* __restrict__ BT,
               const float* __restrict__ bias,
               const unsigned short* __restrict__ res,
               const float* __restrict__ lng,
               const float* __restrict__ lnb,
               void* __restrict__ outv, int M, int NC)
{
    __shared__ unsigned short As[128 * 64];
    __shared__ unsigned short Bs[128 * 64];
    const int tid  = threadIdx.x;
    const int lane = tid & 63;
    const int wid  = tid >> 6;
    const int wr = wid >> 1, wc = wid & 1;
    const int rowBase = blockIdx.x * 128;
    const int colBase = blockIdx.y * 128;

    f32x4 acc[4][4];
#pragma unroll
    for (int i = 0; i < 4; ++i)
#pragma unroll
        for (int j = 0; j < 4; ++j) acc[i][j] = (f32x4)0.f;

    int srow[4], skoff[4];
#pragma unroll
    for (int t = 0; t < 4; ++t) {
        int c = tid + t * 256;
        int r = c >> 3, cc = c & 7;
        srow[t]  = r;
        skoff[t] = ((cc ^ (r & 7)) << 3);
    }

    const int rl = lane & 15;
    const int kh = lane >> 4;

    for (int k0 = 0; k0 < K; k0 += 64) {
#pragma unroll
        for (int t = 0; t < 4; ++t) {
            int c = tid + t * 256;
            gload_lds16(A + (size_t)(rowBase + srow[t]) * K + k0 + skoff[t], &As[c * 8]);
            gload_lds16(BT + (size_t)(colBase + srow[t]) * K + k0 + skoff[t], &Bs[c * 8]);
        }
        __syncthreads();

        bf16x8 a[4][2], b[4][2];
#pragma unroll
        for (int mi = 0; mi < 4; ++mi)
#pragma unroll
            for (int kt = 0; kt < 2; ++kt) {
                a[mi][kt] = *(const bf16x8*)&As[(((wr * 64 + mi * 16 + rl) * 64) + kt * 32 + kh * 8) ^ ((rl & 7) << 3)];
                b[mi][kt] = *(const bf16x8*)&Bs[(((wc * 64 + mi * 16 + rl) * 64) + kt * 32 + kh * 8) ^ ((rl & 7) << 3)];
            }
#pragma unroll
        for (int kt = 0; kt < 2; ++kt)
#pragma unroll
            for (int mi = 0; mi < 4; ++mi)
#pragma unroll
                for (int ni = 0; ni < 4; ++ni)
                    acc[mi][ni] = __builtin_amdgcn_mfma_f32_16x16x32_bf16(a[mi][kt], b[ni][kt], acc[mi][ni], 0, 0, 0);
        __syncthreads();
    }

    if (EPI == 3 || EPI == 4) {
        float* ls = (float*)As;
        float bb[4], gg[4], be[4];
#pragma unroll
        for (int ni = 0; ni < 4; ++ni) {
            int col = wc * 64 + ni * 16 + rl;
            bb[ni] = bias[col];
            gg[ni] = lng[col];
            be[ni] = lnb[col];
        }
#pragma unroll
        for (int mi = 0; mi < 4; ++mi) {
#pragma unroll
            for (int r = 0; r < 4; ++r) {
                int lrow = wr * 64 + mi * 16 + kh * 4 + r;
                int row  = rowBase + lrow;
                float s = 0.f, ss = 0.f;
#pragma unroll
                for (int ni = 0; ni < 4; ++ni) {
                    int col = wc * 64 + ni * 16 + rl;
                    float rr = 0.f;
                    if (row < M) rr = b2f(res[(size_t)row * 128 + col]);
                    float v = acc[mi][ni][r] + bb[ni] + rr;
                    acc[mi][ni][r] = v;
                    s += v; ss += v * v;
                }
#pragma unroll
                for (int off = 1; off < 16; off <<= 1) {
                    s  += __shfl_xor(s,  off, 64);
                    ss += __shfl_xor(ss, off, 64);
                }
                if (rl == 0) {
                    ls[lrow * 2 + wc]       = s;
                    ls[256 + lrow * 2 + wc] = ss;
                }
            }
        }
        __syncthreads();
#pragma unroll
        for (int mi = 0; mi < 4; ++mi) {
#pragma unroll
            for (int r = 0; r < 4; ++r) {
                int lrow = wr * 64 + mi * 16 + kh * 4 + r;
                int row  = rowBase + lrow;
                float s  = ls[lrow * 2] + ls[lrow * 2 + 1];
                float ss = ls[256 + lrow * 2] + ls[256 + lrow * 2 + 1];
                float mean = s * (1.f / 128.f);
                float var  = ss * (1.f / 128.f) - mean * mean;
                float rstd = rsqrtf(var + 1e-5f);
#pragma unroll
                for (int ni = 0; ni < 4; ++ni) {
                    int col = wc * 64 + ni * 16 + rl;
                    float o = (acc[mi][ni][r] - mean) * rstd * gg[ni] + be[ni];
                    if (EPI == 3) {
                        ((unsigned short*)outv)[(size_t)row * 128 + col] = (row < M) ? f2b(o) : (unsigned short)0;
                    } else {
                        if (row < M) ((float*)outv)[(size_t)row * 128 + col] = o;
                    }
                }
            }
        }
    } else {
#pragma unroll
        for (int ni = 0; ni < 4; ++ni) {
            const int col = colBase + wc * 64 + ni * 16 + rl;
            const float bv = bias[col];
#pragma unroll
            for (int mi = 0; mi < 4; ++mi) {
                const int rowb = rowBase + wr * 64 + mi * 16 + kh * 4;
#pragma unroll
                for (int r = 0; r < 4; ++r) {
                    float v = acc[mi][ni][r] + bv;
                    if (EPI == 1) v = fmaxf(v, 0.f);
                    ((unsigned short*)outv)[(size_t)(rowb + r) * NC + col] = f2b(v);
                }
            }
        }
    }
}

// ---------------------------------------------------------------------------
// fused input casts + bcnt/bcur zeroing
// ---------------------------------------------------------------------------
__global__ void cast_all(const float* __restrict__ x, unsigned short* __restrict__ xb,
                         int n, int npad, int xblocks,
                         const float* __restrict__ Wq, const float* __restrict__ Wk,
                         const float* __restrict__ Wv, const float* __restrict__ Wo,
                         const float* __restrict__ W1, const float* __restrict__ W2,
                         const float* __restrict__ bq, const float* __restrict__ bk,
                         const float* __restrict__ bv,
                         unsigned short* __restrict__ WcatT, unsigned short* __restrict__ WoT,
                         unsigned short* __restrict__ W1T, unsigned short* __restrict__ W2T,
                         float* __restrict__ bqkv, int* __restrict__ bcnt)
{
    if (blockIdx.x < (unsigned)xblocks) {
        size_t i = ((size_t)blockIdx.x * 256 + threadIdx.x) * 4;
        if (i >= (size_t)npad * 128) return;
        float4 v = make_float4(0.f, 0.f, 0.f, 0.f);
        if (i < (size_t)n * 128) v = *(const float4*)(x + i);
        ushort4 o;
        o.x = f2b(v.x); o.y = f2b(v.y); o.z = f2b(v.z); o.w = f2b(v.w);
        *(ushort4*)(xb + i) = o;
        return;
    }
    int i = (blockIdx.x - xblocks) * 256 + threadIdx.x;
    if (i < 49152) {
        int j = i >> 7, k = i & 127;
        const float* W = (j < 128) ? Wq : ((j < 256) ? Wk : Wv);
        WcatT[i] = f2b(W[k * 128 + (j & 127)]);
    } else if (i < 65536) {
        int t = i - 49152; int j = t >> 7, k = t & 127;
        WoT[t] = f2b(Wo[k * 128 + j]);
    } else if (i < 131072) {
        int t = i - 65536; int j = t >> 7, k = t & 127;
        W1T[t] = f2b(W1[k * 512 + j]);
    } else if (i < 196608) {
        int t = i - 131072; int j = t >> 9, k = t & 511;
        W2T[t] = f2b(W2[k * 128 + j]);
    }
    if (i < 384) bqkv[i] = (i < 128) ? bq[i] : ((i < 256) ? bk[i - 128] : bv[i - 256]);
    if (i < 2048) bcnt[i] = 0;    // bcnt[1024] | bcur[1024]
}

// ---------------------------------------------------------------------------
// Bucketed counting sort of edges by target (bucket = 64 targets).
// Edge record packed: (src<<16)|tgt  (valid: N <= 65536).
// ---------------------------------------------------------------------------
#define EPB 8192   // edges per grouping block

__global__ __launch_bounds__(512)
void bucket_count(const int* __restrict__ tgt, int* __restrict__ bcnt, int E, int nb)
{
    __shared__ int hist[1024];
    int base = blockIdx.x * EPB;
    for (int i = threadIdx.x; i < nb; i += 512) hist[i] = 0;
    __syncthreads();
    int end = min(base + EPB, E);
    for (int e = base + threadIdx.x; e < end; e += 512)
        atomicAdd(&hist[tgt[e] >> 6], 1);
    __syncthreads();
    for (int i = threadIdx.x; i < nb; i += 512)
        if (hist[i] > 0) atomicAdd(&bcnt[i], hist[i]);
}

// 64-wide chunked exclusive scan of src[0..nb) -> dst (LDS), by threads 0..63
__device__ __forceinline__ void scan1024(const int* __restrict__ src, int* dst,
                                         int nb, int tid)
{
    if (tid < 64) {
        int carry = 0;
        for (int c = 0; c < nb; c += 64) {
            int idx = c + tid;
            int v = (idx < nb) ? src[idx] : 0;
            int orig = v;
#pragma unroll
            for (int off = 1; off < 64; off <<= 1) {
                int y = __shfl_up(v, off, 64);
                if (tid >= off) v += y;
            }
            if (idx < nb) dst[idx] = carry + v - orig;
            carry += __shfl(v, 63, 64);
        }
    }
}

__global__ __launch_bounds__(512)
void bucket_group(const int* __restrict__ src, const int* __restrict__ tgt,
                  const int* __restrict__ bcnt, int* __restrict__ bcur,
                  unsigned int* __restrict__ stage, int E, int nb)
{
    __shared__ unsigned int eb[EPB];               // 32 KB
    __shared__ int hist[1024], lofs[1024], lcur[1024], gbase[1024], bst[1024];
    int base = blockIdx.x * EPB;
    int tid = threadIdx.x;
    for (int i = tid; i < nb; i += 512) { hist[i] = 0; lcur[i] = 0; }
    __syncthreads();
    int end = min(base + EPB, E);
    for (int e = base + tid; e < end; e += 512)
        atomicAdd(&hist[tgt[e] >> 6], 1);
    __syncthreads();
    scan1024(hist, lofs, nb, tid);                 // local offsets
    scan1024(bcnt, bst, nb, tid);                  // global bucket starts
    __syncthreads();
    for (int e = base + tid; e < end; e += 512) {
        int t = tgt[e], b = t >> 6;
        int r = atomicAdd(&lcur[b], 1);
        eb[lofs[b] + r] = ((unsigned int)src[e] << 16) | (unsigned int)t;
    }
    __syncthreads();
    for (int i = tid; i < nb; i += 512)
        if (hist[i] > 0) gbase[i] = bst[i] + atomicAdd(&bcur[i], hist[i]);
    __syncthreads();
    int cnt = end - base;
    for (int i = tid; i < cnt; i += 512) {
        unsigned int v = eb[i];
        int b = (v & 0xFFFFu) >> 6;
        stage[gbase[b] + (i - lofs[b])] = v;
    }
}

// One block per bucket: local scan for bucket start, LDS counting sort,
// writes rowp slice + packed sorted records.
__global__ __launch_bounds__(256)
void bucket_sort(const unsigned int* __restrict__ stage, const int* __restrict__ bcnt,
                 int* __restrict__ rowp, unsigned int* __restrict__ spk, int n, int nb)
{
    __shared__ unsigned int eb[3072], eb2[3072];   // 24 KB
    __shared__ int bst[1024];
    __shared__ int tcnt[64], tofs[64], tcur[64];
    int b = blockIdx.x;
    int t0 = b << 6;
    if (t0 >= n) return;
    int t1 = min(t0 + 64, n);
    int tid = threadIdx.x;
    scan1024(bcnt, bst, nb, tid);
    if (tid < 64) { tcnt[tid] = 0; tcur[tid] = 0; }
    __syncthreads();
    int s0 = bst[b], s1 = s0 + bcnt[b];
    int cnt = s1 - s0;
    bool fits = (cnt <= 3072);
    if (fits) {
        for (int i = tid; i < cnt; i += 256) {
            unsigned int v = stage[s0 + i];
            eb[i] = v;
            atomicAdd(&tcnt[(v & 0xFFFFu) - t0], 1);
        }
    } else {
        for (int i = tid; i < cnt; i += 256)
            atomicAdd(&tcnt[(stage[s0 + i] & 0xFFFFu) - t0], 1);
    }
    __syncthreads();
    if (tid < 64) {
        int v = tcnt[tid], orig = v;
#pragma unroll
        for (int off = 1; off < 64; off <<= 1) {
            int y = __shfl_up(v, off, 64);
            if (tid >= off) v += y;
        }
        tofs[tid] = v - orig;                      // exclusive
        int t = t0 + tid;
        if (t < t1) rowp[t] = s0 + v - orig;
        if (t == n - 1) rowp[n] = s1;
    }
    __syncthreads();
    if (fits) {
        for (int i = tid; i < cnt; i += 256) {
            unsigned int v = eb[i];
            int lt = (v & 0xFFFFu) - t0;
            int r = atomicAdd(&tcur[lt], 1);
            eb2[tofs[lt] + r] = v;
        }
        __syncthreads();
        for (int i = tid; i < cnt; i += 256) spk[s0 + i] = eb2[i];
    } else {
        for (int i = tid; i < cnt; i += 256) {
            unsigned int v = stage[s0 + i];
            int lt = (v & 0xFFFFu) - t0;
            int r = atomicAdd(&tcur[lt], 1);
            spk[s0 + tofs[lt] + r] = v;
        }
    }
}

// ---------------------------------------------------------------------------
// Edge-parallel score kernel: 16 lanes per sorted edge. Writes UNNORMALIZED
// softmax weights exp2(score*log2e/4) as bf16 (no max pass: |score| small so
// exp is safe in f32; softmax is shift-invariant so result matches ref).
// ---------------------------------------------------------------------------
#define SCORE_SCALE 0.360673760222241f   // 0.25 * log2(e)

__global__ __launch_bounds__(256)
void score_kernel(const unsigned short* __restrict__ qkv, const unsigned int* __restrict__ spk,
                  unsigned short* __restrict__ wexp, int E)
{
    int gw = (blockIdx.x * 256 + threadIdx.x) >> 4;
    int el = threadIdx.x & 15;
    if (gw >= E) return;
    unsigned int st = spk[gw];
    int srcn = st >> 16, tgtn = st & 0xFFFFu;
    uint4 qv = *(const uint4*)(qkv + (size_t)tgtn * 384 + el * 8);
    uint4 kv = *(const uint4*)(qkv + (size_t)srcn * 384 + 128 + el * 8);
    float d;
    d  = blo(qv.x) * blo(kv.x) + bhi(qv.x) * bhi(kv.x);
    d += blo(qv.y) * blo(kv.y) + bhi(qv.y) * bhi(kv.y);
    d += blo(qv.z) * blo(kv.z) + bhi(qv.z) * bhi(kv.z);
    d += blo(qv.w) * blo(kv.w) + bhi(qv.w) * bhi(kv.w);
    d += __shfl_xor(d, 1, 64);
    if ((el & 1) == 0)
        wexp[(size_t)gw * 8 + (el >> 1)] = f2b(exp2f(d * SCORE_SCALE));
}

// ---------------------------------------------------------------------------
// Aggregation: ONE wave per target, pure weighted V-gather with pre-exp'd
// bf16 weights, 16-edge unroll for deep load ILP (latency-bound kernel).
// Lane holds dims 2l,2l+1; head = lane>>3.
// ---------------------------------------------------------------------------
__global__ __launch_bounds__(256)
void attn_agg(const unsigned short* __restrict__ qkv, const int* __restrict__ rowp,
              const unsigned int* __restrict__ spk, const unsigned short* __restrict__ wexp,
              unsigned short* __restrict__ agg, int n, int npad)
{
    int wid  = (blockIdx.x * blockDim.x + threadIdx.x) >> 6;
    int lane = threadIdx.x & 63;
    if (wid >= npad) return;
    if (wid >= n) { *(unsigned int*)(agg + (size_t)wid * 128 + lane * 2) = 0u; return; }

    const int head = lane >> 3;
    int e = rowp[wid];
    const int e1 = rowp[wid + 1];

    float s = 0.f, a0 = 0.f, a1 = 0.f;

    for (; e + 16 <= e1; e += 16) {
        int sx[16];
        float w[16];
        unsigned int v[16];
#pragma unroll
        for (int u = 0; u < 16; ++u) sx[u] = spk[e + u] >> 16;
#pragma unroll
        for (int u = 0; u < 16; ++u) w[u] = b2f(wexp[(size_t)(e + u) * 8 + head]);
#pragma unroll
        for (int u = 0; u < 16; ++u)
            v[u] = *(const unsigned int*)(qkv + (size_t)sx[u] * 384 + 256 + lane * 2);
#pragma unroll
        for (int u = 0; u < 16; ++u) {
            s  += w[u];
            a0 += w[u] * blo(v[u]);
            a1 += w[u] * bhi(v[u]);
        }
    }
    for (; e + 4 <= e1; e += 4) {
        int s0 = spk[e] >> 16, s1 = spk[e + 1] >> 16, s2 = spk[e + 2] >> 16, s3 = spk[e + 3] >> 16;
        float w0 = b2f(wexp[(size_t)e * 8 + head]);
        float w1 = b2f(wexp[(size_t)(e + 1) * 8 + head]);
        float w2 = b2f(wexp[(size_t)(e + 2) * 8 + head]);
        float w3 = b2f(wexp[(size_t)(e + 3) * 8 + head]);
        unsigned int v0 = *(const unsigned int*)(qkv + (size_t)s0 * 384 + 256 + lane * 2);
        unsigned int v1 = *(const unsigned int*)(qkv + (size_t)s1 * 384 + 256 + lane * 2);
        unsigned int v2 = *(const unsigned int*)(qkv + (size_t)s2 * 384 + 256 + lane * 2);
        unsigned int v3 = *(const unsigned int*)(qkv + (size_t)s3 * 384 + 256 + lane * 2);
        s  += (w0 + w1) + (w2 + w3);
        a0 += (w0 * blo(v0) + w1 * blo(v1)) + (w2 * blo(v2) + w3 * blo(v3));
        a1 += (w0 * bhi(v0) + w1 * bhi(v1)) + (w2 * bhi(v2) + w3 * bhi(v3));
    }
    for (; e < e1; ++e) {
        int sx = spk[e] >> 16;
        float w = b2f(wexp[(size_t)e * 8 + head]);
        unsigned int vw = *(const unsigned int*)(qkv + (size_t)sx * 384 + 256 + lane * 2);
        s  += w;
        a0 += w * blo(vw);
        a1 += w * bhi(vw);
    }
    float inv = 1.f / (s + 1e-16f);
    unsigned int o = (unsigned int)f2b(a0 * inv) | ((unsigned int)f2b(a1 * inv) << 16);
    *(unsigned int*)(agg + (size_t)wid * 128 + lane * 2) = o;
}

// ---------------------------------------------------------------------------
extern "C" void kernel_launch(void* const* d_in, const int* in_sizes, int n_in,
                              void* d_out, int out_size, void* d_ws, size_t ws_size,
                              hipStream_t stream)
{
    const float* x    = (const float*)d_in[0];
    const float* Wq   = (const float*)d_in[1];
    const float* bq   = (const float*)d_in[2];
    const float* Wk   = (const float*)d_in[3];
    const float* bk   = (const float*)d_in[4];
    const float* Wv   = (const float*)d_in[5];
    const float* bv   = (const float*)d_in[6];
    const float* Wo   = (const float*)d_in[7];
    const float* bo   = (const float*)d_in[8];
    const float* ln1g = (const float*)d_in[9];
    const float* ln1b = (const float*)d_in[10];
    const float* W1   = (const float*)d_in[11];
    const float* b1   = (const float*)d_in[12];
    const float* W2   = (const float*)d_in[13];
    const float* b2   = (const float*)d_in[14];
    const float* ln2g = (const float*)d_in[15];
    const float* ln2b = (const float*)d_in[16];
    const int*   eidx = (const int*)d_in[17];

    const int N_ = in_sizes[0] / 128;       // 50000 (< 65536: packed-record assumption)
    const int E_ = in_sizes[17] / 2;
    const int Mpad = ((N_ + 127) / 128) * 128;
    const int nb = (N_ + 63) >> 6;          // buckets of 64 targets (<=1024)
    const int* srcE = eidx;
    const int* tgtE = eidx + E_;
    float* out = (float*)d_out;

    // workspace layout
    unsigned short* xb   = (unsigned short*)d_ws;                 // [Mpad][128]
    unsigned short* qkvb = xb + (size_t)Mpad * 128;               // [Mpad][384]
    unsigned short* tb   = xb;                                    // alias [Mpad][512] (FF1 phase; xb dead after Wo)
    unsigned short* aggb = qkvb + (size_t)Mpad * 384;             // [Mpad][128]
    unsigned short* hb   = aggb + (size_t)Mpad * 128;             // [Mpad][128]
    unsigned short* wexp = hb + (size_t)Mpad * 128;               // [E][8] bf16 exp-weights
    unsigned short* WcatT = wexp + (size_t)E_ * 8;
    unsigned short* WoT  = WcatT + 384 * 128;
    unsigned short* W1T  = WoT + 128 * 128;
    unsigned short* W2T  = W1T + 512 * 128;
    float* bqkv          = (float*)(W2T + 128 * 512);
    unsigned int* stage  = (unsigned int*)(bqkv + 384);           // [E] packed
    unsigned int* spk    = stage + E_;                            // [E] packed sorted
    int* bcnt   = (int*)(spk + E_);                               // [1024]
    int* bcur   = bcnt + 1024;                                    // [1024] (zeroed with bcnt)
    int* rowp   = bcur + 1024;                                    // [N+1]

    const int xblocks = (int)(((size_t)Mpad * 128 / 4 + 255) / 256);
    const int gblocks = (E_ + EPB - 1) / EPB;

    cast_all<<<xblocks + 768, 256, 0, stream>>>(x, xb, N_, Mpad, xblocks,
                                                Wq, Wk, Wv, Wo, W1, W2, bq, bk, bv,
                                                WcatT, WoT, W1T, W2T, bqkv, bcnt);

    // QKV fused GEMM: [Mpad x 128] @ [128 x 384]
    mfma_gemm<128, 2><<<dim3(Mpad / 128, 3), 256, 0, stream>>>(
        xb, WcatT, bqkv, nullptr, nullptr, nullptr, qkvb, N_, 384);

    // edge sort by target (scan folded into group/sort as local LDS scans)
    bucket_count<<<gblocks, 512, 0, stream>>>(tgtE, bcnt, E_, nb);
    bucket_group<<<gblocks, 512, 0, stream>>>(srcE, tgtE, bcnt, bcur, stage, E_, nb);
    bucket_sort<<<nb, 256, 0, stream>>>(stage, bcnt, rowp, spk, N_, nb);

    // attention: exp-weights then 1-wave-per-target weighted gather
    score_kernel<<<((size_t)E_ * 16 + 255) / 256, 256, 0, stream>>>(qkvb, spk, wexp, E_);
    attn_agg<<<(Mpad + 3) / 4, 256, 0, stream>>>(qkvb, rowp, spk, wexp, aggb, N_, Mpad);

    // Wo GEMM + residual(xb, bf16) + LN1 -> hb (bf16)
    mfma_gemm<128, 3><<<dim3(Mpad / 128, 1), 256, 0, stream>>>(
        aggb, WoT, bo, xb, ln1g, ln1b, hb, N_, 128);

    // FF1: relu(h @ W1 + b1) -> tb (bf16)
    mfma_gemm<128, 1><<<dim3(Mpad / 128, 4), 256, 0, stream>>>(
        hb, W1T, b1, nullptr, nullptr, nullptr, tb, N_, 512);

    // FF2 + residual(hb) + LN2 -> out (f32)
    mfma_gemm<512, 4><<<dim3(Mpad / 128, 1), 256, 0, stream>>>(
        tb, W2T, b2, hb, ln2g, ln2b, out, N_, 128);
}

// Round 13
// 209.425 us; speedup vs baseline: 1.0219x; 1.0219x over previous
//
#include <hip/hip_runtime.h>
#include <math.h>

typedef __attribute__((ext_vector_type(8))) short bf16x8;
typedef __attribute__((ext_vector_type(4))) float f32x4;

__device__ __forceinline__ unsigned short f2b(float f) {
    unsigned int u = __float_as_uint(f);
    unsigned int r = (u + 0x7fffu + ((u >> 16) & 1u)) >> 16;   // RTNE
    return (unsigned short)r;
}
__device__ __forceinline__ float blo(unsigned int w) { return __uint_as_float(w << 16); }
__device__ __forceinline__ float bhi(unsigned int w) { return __uint_as_float(w & 0xffff0000u); }
__device__ __forceinline__ float b2f(unsigned short u) { return __uint_as_float((unsigned int)u << 16); }

__device__ __forceinline__ void gload_lds16(const void* g, void* lds) {
    __builtin_amdgcn_global_load_lds(
        (const __attribute__((address_space(1))) unsigned int*)g,
        (__attribute__((address_space(3))) unsigned int*)lds, 16, 0, 0);
}

// ---------------------------------------------------------------------------
// bf16 MFMA GEMM: out[M x NC] = epi(A[Mpad x K] @ W[K x NC] + bias)
// BT = W^T row-major [NC x K] bf16. Tile 128x128, BK=64, 4 waves, T2 swizzle.
// Single-buffered LDS (32 KB) -- 64KB double-buffer costs occupancy (r6).
// EPI: 1 = relu -> bf16 ws (unguarded, Mpad rows)
//      2 = bias -> bf16 ws (unguarded, Mpad rows)
//      3 = +res(bf16) + LayerNorm -> bf16 ws (pad rows zeroed)  [NC==128]
//      4 = +res(bf16) + LayerNorm -> f32 out (guard row<M)      [NC==128]
// ---------------------------------------------------------------------------
template<int K, int EPI>
__global__ __launch_bounds__(256)
void mfma_gemm(const unsigned short* __restrict__ A,
               const unsigned short* __restrict__ BT,
               const float* __restrict__ bias,
               const unsigned short* __restrict__ res,
               const float* __restrict__ lng,
               const float* __restrict__ lnb,
               void* __restrict__ outv, int M, int NC)
{
    __shared__ unsigned short As[128 * 64];
    __shared__ unsigned short Bs[128 * 64];
    const int tid  = threadIdx.x;
    const int lane = tid & 63;
    const int wid  = tid >> 6;
    const int wr = wid >> 1, wc = wid & 1;
    const int rowBase = blockIdx.x * 128;
    const int colBase = blockIdx.y * 128;

    f32x4 acc[4][4];
#pragma unroll
    for (int i = 0; i < 4; ++i)
#pragma unroll
        for (int j = 0; j < 4; ++j) acc[i][j] = (f32x4)0.f;

    int srow[4], skoff[4];
#pragma unroll
    for (int t = 0; t < 4; ++t) {
        int c = tid + t * 256;
        int r = c >> 3, cc = c & 7;
        srow[t]  = r;
        skoff[t] = ((cc ^ (r & 7)) << 3);
    }

    const int rl = lane & 15;
    const int kh = lane >> 4;

    for (int k0 = 0; k0 < K; k0 += 64) {
#pragma unroll
        for (int t = 0; t < 4; ++t) {
            int c = tid + t * 256;
            gload_lds16(A + (size_t)(rowBase + srow[t]) * K + k0 + skoff[t], &As[c * 8]);
            gload_lds16(BT + (size_t)(colBase + srow[t]) * K + k0 + skoff[t], &Bs[c * 8]);
        }
        __syncthreads();

        bf16x8 a[4][2], b[4][2];
#pragma unroll
        for (int mi = 0; mi < 4; ++mi)
#pragma unroll
            for (int kt = 0; kt < 2; ++kt) {
                a[mi][kt] = *(const bf16x8*)&As[(((wr * 64 + mi * 16 + rl) * 64) + kt * 32 + kh * 8) ^ ((rl & 7) << 3)];
                b[mi][kt] = *(const bf16x8*)&Bs[(((wc * 64 + mi * 16 + rl) * 64) + kt * 32 + kh * 8) ^ ((rl & 7) << 3)];
            }
#pragma unroll
        for (int kt = 0; kt < 2; ++kt)
#pragma unroll
            for (int mi = 0; mi < 4; ++mi)
#pragma unroll
                for (int ni = 0; ni < 4; ++ni)
                    acc[mi][ni] = __builtin_amdgcn_mfma_f32_16x16x32_bf16(a[mi][kt], b[ni][kt], acc[mi][ni], 0, 0, 0);
        __syncthreads();
    }

    if (EPI == 3 || EPI == 4) {
        float* ls = (float*)As;
        float bb[4], gg[4], be[4];
#pragma unroll
        for (int ni = 0; ni < 4; ++ni) {
            int col = wc * 64 + ni * 16 + rl;
            bb[ni] = bias[col];
            gg[ni] = lng[col];
            be[ni] = lnb[col];
        }
#pragma unroll
        for (int mi = 0; mi < 4; ++mi) {
#pragma unroll
            for (int r = 0; r < 4; ++r) {
                int lrow = wr * 64 + mi * 16 + kh * 4 + r;
                int row  = rowBase + lrow;
                float s = 0.f, ss = 0.f;
#pragma unroll
                for (int ni = 0; ni < 4; ++ni) {
                    int col = wc * 64 + ni * 16 + rl;
                    float rr = 0.f;
                    if (row < M) rr = b2f(res[(size_t)row * 128 + col]);
                    float v = acc[mi][ni][r] + bb[ni] + rr;
                    acc[mi][ni][r] = v;
                    s += v; ss += v * v;
                }
#pragma unroll
                for (int off = 1; off < 16; off <<= 1) {
                    s  += __shfl_xor(s,  off, 64);
                    ss += __shfl_xor(ss, off, 64);
                }
                if (rl == 0) {
                    ls[lrow * 2 + wc]       = s;
                    ls[256 + lrow * 2 + wc] = ss;
                }
            }
        }
        __syncthreads();
#pragma unroll
        for (int mi = 0; mi < 4; ++mi) {
#pragma unroll
            for (int r = 0; r < 4; ++r) {
                int lrow = wr * 64 + mi * 16 + kh * 4 + r;
                int row  = rowBase + lrow;
                float s  = ls[lrow * 2] + ls[lrow * 2 + 1];
                float ss = ls[256 + lrow * 2] + ls[256 + lrow * 2 + 1];
                float mean = s * (1.f / 128.f);
                float var  = ss * (1.f / 128.f) - mean * mean;
                float rstd = rsqrtf(var + 1e-5f);
#pragma unroll
                for (int ni = 0; ni < 4; ++ni) {
                    int col = wc * 64 + ni * 16 + rl;
                    float o = (acc[mi][ni][r] - mean) * rstd * gg[ni] + be[ni];
                    if (EPI == 3) {
                        ((unsigned short*)outv)[(size_t)row * 128 + col] = (row < M) ? f2b(o) : (unsigned short)0;
                    } else {
                        if (row < M) ((float*)outv)[(size_t)row * 128 + col] = o;
                    }
                }
            }
        }
    } else {
#pragma unroll
        for (int ni = 0; ni < 4; ++ni) {
            const int col = colBase + wc * 64 + ni * 16 + rl;
            const float bv = bias[col];
#pragma unroll
            for (int mi = 0; mi < 4; ++mi) {
                const int rowb = rowBase + wr * 64 + mi * 16 + kh * 4;
#pragma unroll
                for (int r = 0; r < 4; ++r) {
                    float v = acc[mi][ni][r] + bv;
                    if (EPI == 1) v = fmaxf(v, 0.f);
                    ((unsigned short*)outv)[(size_t)(rowb + r) * NC + col] = f2b(v);
                }
            }
        }
    }
}

// ---------------------------------------------------------------------------
// fused input casts + bcnt zeroing
// ---------------------------------------------------------------------------
__global__ void cast_all(const float* __restrict__ x, unsigned short* __restrict__ xb,
                         int n, int npad, int xblocks,
                         const float* __restrict__ Wq, const float* __restrict__ Wk,
                         const float* __restrict__ Wv, const float* __restrict__ Wo,
                         const float* __restrict__ W1, const float* __restrict__ W2,
                         const float* __restrict__ bq, const float* __restrict__ bk,
                         const float* __restrict__ bv,
                         unsigned short* __restrict__ WcatT, unsigned short* __restrict__ WoT,
                         unsigned short* __restrict__ W1T, unsigned short* __restrict__ W2T,
                         float* __restrict__ bqkv, int* __restrict__ bcnt)
{
    if (blockIdx.x < (unsigned)xblocks) {
        size_t i = ((size_t)blockIdx.x * 256 + threadIdx.x) * 4;
        if (i >= (size_t)npad * 128) return;
        float4 v = make_float4(0.f, 0.f, 0.f, 0.f);
        if (i < (size_t)n * 128) v = *(const float4*)(x + i);
        ushort4 o;
        o.x = f2b(v.x); o.y = f2b(v.y); o.z = f2b(v.z); o.w = f2b(v.w);
        *(ushort4*)(xb + i) = o;
        return;
    }
    int i = (blockIdx.x - xblocks) * 256 + threadIdx.x;
    if (i < 49152) {
        int j = i >> 7, k = i & 127;
        const float* W = (j < 128) ? Wq : ((j < 256) ? Wk : Wv);
        WcatT[i] = f2b(W[k * 128 + (j & 127)]);
    } else if (i < 65536) {
        int t = i - 49152; int j = t >> 7, k = t & 127;
        WoT[t] = f2b(Wo[k * 128 + j]);
    } else if (i < 131072) {
        int t = i - 65536; int j = t >> 7, k = t & 127;
        W1T[t] = f2b(W1[k * 512 + j]);
    } else if (i < 196608) {
        int t = i - 131072; int j = t >> 9, k = t & 511;
        W2T[t] = f2b(W2[k * 128 + j]);
    }
    if (i < 384) bqkv[i] = (i < 128) ? bq[i] : ((i < 256) ? bk[i - 128] : bv[i - 256]);
    if (i < 1024) bcnt[i] = 0;
}

// ---------------------------------------------------------------------------
// Bucketed counting sort of edges by target (bucket = 64 targets).
// Edge record packed: (src<<16)|tgt  (valid: N <= 65536).
// ---------------------------------------------------------------------------
#define EPB 8192   // edges per grouping block

__global__ __launch_bounds__(512)
void bucket_count(const int* __restrict__ tgt, int* __restrict__ bcnt, int E, int nb)
{
    __shared__ int hist[1024];
    int base = blockIdx.x * EPB;
    for (int i = threadIdx.x; i < nb; i += 512) hist[i] = 0;
    __syncthreads();
    int end = min(base + EPB, E);
    for (int e = base + threadIdx.x; e < end; e += 512)
        atomicAdd(&hist[tgt[e] >> 6], 1);
    __syncthreads();
    for (int i = threadIdx.x; i < nb; i += 512)
        if (hist[i] > 0) atomicAdd(&bcnt[i], hist[i]);
}

__global__ __launch_bounds__(64)
void bucket_scan(const int* __restrict__ bcnt, int* __restrict__ bstart,
                 int* __restrict__ bcur, int nb, int E)
{
    int lane = threadIdx.x;
    int carry = 0;
    for (int c = 0; c < nb; c += 64) {
        int idx = c + lane;
        int v = (idx < nb) ? bcnt[idx] : 0;
        int orig = v;
#pragma unroll
        for (int off = 1; off < 64; off <<= 1) {
            int y = __shfl_up(v, off, 64);
            if (lane >= off) v += y;
        }
        if (idx < nb) { int ex = carry + v - orig; bstart[idx] = ex; bcur[idx] = ex; }
        carry += __shfl(v, 63, 64);
    }
    if (lane == 0) bstart[nb] = E;
}

__global__ __launch_bounds__(512)
void bucket_group(const int* __restrict__ src, const int* __restrict__ tgt,
                  int* __restrict__ bcur, unsigned int* __restrict__ stage, int E, int nb)
{
    __shared__ unsigned int eb[EPB];               // 32 KB
    __shared__ int hist[1024], lofs[1024], lcur[1024], gbase[1024];
    int base = blockIdx.x * EPB;
    int tid = threadIdx.x;
    for (int i = tid; i < nb; i += 512) { hist[i] = 0; lcur[i] = 0; }
    __syncthreads();
    int end = min(base + EPB, E);
    for (int e = base + tid; e < end; e += 512)
        atomicAdd(&hist[tgt[e] >> 6], 1);
    __syncthreads();
    if (tid < 64) {
        int carry = 0;
        for (int c = 0; c < nb; c += 64) {
            int idx = c + tid;
            int v = (idx < nb) ? hist[idx] : 0;
            int orig = v;
#pragma unroll
            for (int off = 1; off < 64; off <<= 1) {
                int y = __shfl_up(v, off, 64);
                if (tid >= off) v += y;
            }
            if (idx < nb) lofs[idx] = carry + v - orig;
            carry += __shfl(v, 63, 64);
        }
    }
    __syncthreads();
    for (int e = base + tid; e < end; e += 512) {
        int t = tgt[e], b = t >> 6;
        int r = atomicAdd(&lcur[b], 1);
        eb[lofs[b] + r] = ((unsigned int)src[e] << 16) | (unsigned int)t;
    }
    __syncthreads();
    for (int i = tid; i < nb; i += 512)
        if (hist[i] > 0) gbase[i] = atomicAdd(&bcur[i], hist[i]);
    __syncthreads();
    int cnt = end - base;
    for (int i = tid; i < cnt; i += 512) {
        unsigned int v = eb[i];
        int b = (v & 0xFFFFu) >> 6;
        stage[gbase[b] + (i - lofs[b])] = v;
    }
}

__global__ __launch_bounds__(256)
void bucket_sort(const unsigned int* __restrict__ stage, const int* __restrict__ bstart,
                 int* __restrict__ rowp, unsigned int* __restrict__ spk, int n, int nb)
{
    __shared__ unsigned int eb[3072], eb2[3072];   // 24 KB
    __shared__ int tcnt[64], tofs[64], tcur[64];
    int b = blockIdx.x;
    int t0 = b << 6;
    if (t0 >= n) return;
    int t1 = min(t0 + 64, n);
    int s0 = bstart[b], s1 = bstart[b + 1];
    int cnt = s1 - s0;
    int tid = threadIdx.x;
    if (tid < 64) { tcnt[tid] = 0; tcur[tid] = 0; }
    __syncthreads();
    bool fits = (cnt <= 3072);
    if (fits) {
        for (int i = tid; i < cnt; i += 256) {
            unsigned int v = stage[s0 + i];
            eb[i] = v;
            atomicAdd(&tcnt[(v & 0xFFFFu) - t0], 1);
        }
    } else {
        for (int i = tid; i < cnt; i += 256)
            atomicAdd(&tcnt[(stage[s0 + i] & 0xFFFFu) - t0], 1);
    }
    __syncthreads();
    if (tid < 64) {
        int v = tcnt[tid], orig = v;
#pragma unroll
        for (int off = 1; off < 64; off <<= 1) {
            int y = __shfl_up(v, off, 64);
            if (tid >= off) v += y;
        }
        tofs[tid] = v - orig;                      // exclusive
        int t = t0 + tid;
        if (t < t1) rowp[t] = s0 + v - orig;
        if (t == n - 1) rowp[n] = s1;
    }
    __syncthreads();
    if (fits) {
        for (int i = tid; i < cnt; i += 256) {
            unsigned int v = eb[i];
            int lt = (v & 0xFFFFu) - t0;
            int r = atomicAdd(&tcur[lt], 1);
            eb2[tofs[lt] + r] = v;
        }
        __syncthreads();
        for (int i = tid; i < cnt; i += 256) spk[s0 + i] = eb2[i];
    } else {
        for (int i = tid; i < cnt; i += 256) {
            unsigned int v = stage[s0 + i];
            int lt = (v & 0xFFFFu) - t0;
            int r = atomicAdd(&tcur[lt], 1);
            spk[s0 + tofs[lt] + r] = v;
        }
    }
}

// ---------------------------------------------------------------------------
// Edge-parallel score kernel: 16 lanes per sorted edge. Writes UNNORMALIZED
// softmax weights exp2(score*log2e/4) as bf16 (no max pass: |score| small so
// exp is safe in f32; softmax is shift-invariant so result matches ref).
// ---------------------------------------------------------------------------
#define SCORE_SCALE 0.360673760222241f   // 0.25 * log2(e)

__global__ __launch_bounds__(256)
void score_kernel(const unsigned short* __restrict__ qkv, const unsigned int* __restrict__ spk,
                  unsigned short* __restrict__ wexp, int E)
{
    int gw = (blockIdx.x * 256 + threadIdx.x) >> 4;
    int el = threadIdx.x & 15;
    if (gw >= E) return;
    unsigned int st = spk[gw];
    int srcn = st >> 16, tgtn = st & 0xFFFFu;
    uint4 qv = *(const uint4*)(qkv + (size_t)tgtn * 384 + el * 8);
    uint4 kv = *(const uint4*)(qkv + (size_t)srcn * 384 + 128 + el * 8);
    float d;
    d  = blo(qv.x) * blo(kv.x) + bhi(qv.x) * bhi(kv.x);
    d += blo(qv.y) * blo(kv.y) + bhi(qv.y) * bhi(kv.y);
    d += blo(qv.z) * blo(kv.z) + bhi(qv.z) * bhi(kv.z);
    d += blo(qv.w) * blo(kv.w) + bhi(qv.w) * bhi(kv.w);
    d += __shfl_xor(d, 1, 64);
    if ((el & 1) == 0)
        wexp[(size_t)gw * 8 + (el >> 1)] = f2b(exp2f(d * SCORE_SCALE));
}

// ---------------------------------------------------------------------------
// Aggregation: ONE wave per target, pure weighted V-gather with pre-exp'd
// bf16 weights, 8-edge unroll (r11 config: 20 VGPR, full occupancy --
// r12's 16-unroll pushed past the 64-VGPR occupancy step and regressed).
// Lane holds dims 2l,2l+1; head = lane>>3.
// ---------------------------------------------------------------------------
__global__ __launch_bounds__(256)
void attn_agg(const unsigned short* __restrict__ qkv, const int* __restrict__ rowp,
              const unsigned int* __restrict__ spk, const unsigned short* __restrict__ wexp,
              unsigned short* __restrict__ agg, int n, int npad)
{
    int wid  = (blockIdx.x * blockDim.x + threadIdx.x) >> 6;
    int lane = threadIdx.x & 63;
    if (wid >= npad) return;
    if (wid >= n) { *(unsigned int*)(agg + (size_t)wid * 128 + lane * 2) = 0u; return; }

    const int head = lane >> 3;
    int e = rowp[wid];
    const int e1 = rowp[wid + 1];

    float s = 0.f, a0 = 0.f, a1 = 0.f;

    for (; e + 8 <= e1; e += 8) {
        int sx[8];
        float w[8];
        unsigned int v[8];
#pragma unroll
        for (int u = 0; u < 8; ++u) sx[u] = spk[e + u] >> 16;
#pragma unroll
        for (int u = 0; u < 8; ++u) w[u] = b2f(wexp[(size_t)(e + u) * 8 + head]);
#pragma unroll
        for (int u = 0; u < 8; ++u)
            v[u] = *(const unsigned int*)(qkv + (size_t)sx[u] * 384 + 256 + lane * 2);
#pragma unroll
        for (int u = 0; u < 8; ++u) {
            s  += w[u];
            a0 += w[u] * blo(v[u]);
            a1 += w[u] * bhi(v[u]);
        }
    }
    for (; e + 4 <= e1; e += 4) {
        int s0 = spk[e] >> 16, s1 = spk[e + 1] >> 16, s2 = spk[e + 2] >> 16, s3 = spk[e + 3] >> 16;
        float w0 = b2f(wexp[(size_t)e * 8 + head]);
        float w1 = b2f(wexp[(size_t)(e + 1) * 8 + head]);
        float w2 = b2f(wexp[(size_t)(e + 2) * 8 + head]);
        float w3 = b2f(wexp[(size_t)(e + 3) * 8 + head]);
        unsigned int v0 = *(const unsigned int*)(qkv + (size_t)s0 * 384 + 256 + lane * 2);
        unsigned int v1 = *(const unsigned int*)(qkv + (size_t)s1 * 384 + 256 + lane * 2);
        unsigned int v2 = *(const unsigned int*)(qkv + (size_t)s2 * 384 + 256 + lane * 2);
        unsigned int v3 = *(const unsigned int*)(qkv + (size_t)s3 * 384 + 256 + lane * 2);
        s  += (w0 + w1) + (w2 + w3);
        a0 += (w0 * blo(v0) + w1 * blo(v1)) + (w2 * blo(v2) + w3 * blo(v3));
        a1 += (w0 * bhi(v0) + w1 * bhi(v1)) + (w2 * bhi(v2) + w3 * bhi(v3));
    }
    for (; e < e1; ++e) {
        int sx = spk[e] >> 16;
        float w = b2f(wexp[(size_t)e * 8 + head]);
        unsigned int vw = *(const unsigned int*)(qkv + (size_t)sx * 384 + 256 + lane * 2);
        s  += w;
        a0 += w * blo(vw);
        a1 += w * bhi(vw);
    }
    float inv = 1.f / (s + 1e-16f);
    unsigned int o = (unsigned int)f2b(a0 * inv) | ((unsigned int)f2b(a1 * inv) << 16);
    *(unsigned int*)(agg + (size_t)wid * 128 + lane * 2) = o;
}

// ---------------------------------------------------------------------------
extern "C" void kernel_launch(void* const* d_in, const int* in_sizes, int n_in,
                              void* d_out, int out_size, void* d_ws, size_t ws_size,
                              hipStream_t stream)
{
    const float* x    = (const float*)d_in[0];
    const float* Wq   = (const float*)d_in[1];
    const float* bq   = (const float*)d_in[2];
    const float* Wk   = (const float*)d_in[3];
    const float* bk   = (const float*)d_in[4];
    const float* Wv   = (const float*)d_in[5];
    const float* bv   = (const float*)d_in[6];
    const float* Wo   = (const float*)d_in[7];
    const float* bo   = (const float*)d_in[8];
    const float* ln1g = (const float*)d_in[9];
    const float* ln1b = (const float*)d_in[10];
    const float* W1   = (const float*)d_in[11];
    const float* b1   = (const float*)d_in[12];
    const float* W2   = (const float*)d_in[13];
    const float* b2   = (const float*)d_in[14];
    const float* ln2g = (const float*)d_in[15];
    const float* ln2b = (const float*)d_in[16];
    const int*   eidx = (const int*)d_in[17];

    const int N_ = in_sizes[0] / 128;       // 50000 (< 65536: packed-record assumption)
    const int E_ = in_sizes[17] / 2;
    const int Mpad = ((N_ + 127) / 128) * 128;
    const int nb = (N_ + 63) >> 6;          // buckets of 64 targets (<=1024)
    const int* srcE = eidx;
    const int* tgtE = eidx + E_;
    float* out = (float*)d_out;

    // workspace layout
    unsigned short* xb   = (unsigned short*)d_ws;                 // [Mpad][128]
    unsigned short* qkvb = xb + (size_t)Mpad * 128;               // [Mpad][384]
    unsigned short* tb   = xb;                                    // alias [Mpad][512] (FF1 phase; xb dead after Wo)
    unsigned short* aggb = qkvb + (size_t)Mpad * 384;             // [Mpad][128]
    unsigned short* hb   = aggb + (size_t)Mpad * 128;             // [Mpad][128]
    unsigned short* wexp = hb + (size_t)Mpad * 128;               // [E][8] bf16 exp-weights
    unsigned short* WcatT = wexp + (size_t)E_ * 8;
    unsigned short* WoT  = WcatT + 384 * 128;
    unsigned short* W1T  = WoT + 128 * 128;
    unsigned short* W2T  = W1T + 512 * 128;
    float* bqkv          = (float*)(W2T + 128 * 512);
    unsigned int* stage  = (unsigned int*)(bqkv + 384);           // [E] packed
    unsigned int* spk    = stage + E_;                            // [E] packed sorted
    int* bcnt   = (int*)(spk + E_);                               // [1024]
    int* bstart = bcnt + 1024;                                    // [1025]
    int* bcur   = bstart + 1025;                                  // [1024]
    int* rowp   = bcur + 1024;                                    // [N+1]

    const int xblocks = (int)(((size_t)Mpad * 128 / 4 + 255) / 256);
    const int gblocks = (E_ + EPB - 1) / EPB;

    cast_all<<<xblocks + 768, 256, 0, stream>>>(x, xb, N_, Mpad, xblocks,
                                                Wq, Wk, Wv, Wo, W1, W2, bq, bk, bv,
                                                WcatT, WoT, W1T, W2T, bqkv, bcnt);

    // QKV fused GEMM: [Mpad x 128] @ [128 x 384]
    mfma_gemm<128, 2><<<dim3(Mpad / 128, 3), 256, 0, stream>>>(
        xb, WcatT, bqkv, nullptr, nullptr, nullptr, qkvb, N_, 384);

    // edge sort by target
    bucket_count<<<gblocks, 512, 0, stream>>>(tgtE, bcnt, E_, nb);
    bucket_scan<<<1, 64, 0, stream>>>(bcnt, bstart, bcur, nb, E_);
    bucket_group<<<gblocks, 512, 0, stream>>>(srcE, tgtE, bcur, stage, E_, nb);
    bucket_sort<<<nb, 256, 0, stream>>>(stage, bstart, rowp, spk, N_, nb);

    // attention: exp-weights then 1-wave-per-target weighted gather
    score_kernel<<<((size_t)E_ * 16 + 255) / 256, 256, 0, stream>>>(qkvb, spk, wexp, E_);
    attn_agg<<<(Mpad + 3) / 4, 256, 0, stream>>>(qkvb, rowp, spk, wexp, aggb, N_, Mpad);

    // Wo GEMM + residual(xb, bf16) + LN1 -> hb (bf16)
    mfma_gemm<128, 3><<<dim3(Mpad / 128, 1), 256, 0, stream>>>(
        aggb, WoT, bo, xb, ln1g, ln1b, hb, N_, 128);

    // FF1: relu(h @ W1 + b1) -> tb (bf16)
    mfma_gemm<128, 1><<<dim3(Mpad / 128, 4), 256, 0, stream>>>(
        hb, W1T, b1, nullptr, nullptr, nullptr, tb, N_, 512);

    // FF2 + residual(hb) + LN2 -> out (f32)
    mfma_gemm<512, 4><<<dim3(Mpad / 128, 1), 256, 0, stream>>>(
        tb, W2T, b2, hb, ln2g, ln2b, out, N_, 128);
}